// Round 15
// baseline (341.545 us; speedup 1.0000x reference)
//
#include <hip/hip_runtime.h>
#include <cstdint>
#include <cstddef>

#define KBOX 4096
#define NMS_THRESH 0.6f

typedef unsigned long long u64;

// ---- workspace layout (bytes) ----
static constexpr size_t WS_SB   = 0;        // float4[KBOX]   64 KB  sorted boxes
static constexpr size_t WS_AREA = 65536;    // float[KBOX]    16 KB  sorted areas
static constexpr size_t WS_SS   = 81920;    // float[KBOX]    16 KB  sorted scores
static constexpr size_t WS_ORD  = 98304;    // int[KBOX]      16 KB  sorted orig idx
static constexpr size_t WS_KEYS = 114688;   // u64[KBOX]      32 KB  sort keys
static constexpr size_t WS_MASK = 147456;   // u64[KBOX*64]    2 MB  iou mask

// async global->LDS DMA: 64 lanes x 16 B = 1 KB per call.
// LDS dest must be wave-uniform (HW adds lane*16); global src is per-lane.
__device__ __forceinline__ void gload_lds16(const void* g, void* l) {
    __builtin_amdgcn_global_load_lds(
        (const __attribute__((address_space(1))) void*)g,
        (__attribute__((address_space(3))) void*)l, 16, 0, 0);
}

// Kernel 1: build sort keys. key = (score_bits<<32) | (0xFFFFFFFF - p).
// Scores are positive floats -> uint bit-pattern is order-preserving; low word
// makes keys UNIQUE and reproduces stable argsort(-scores) tie-breaking.
__global__ __launch_bounds__(256) void k_keys(const float* __restrict__ yolo,
                                              const int* __restrict__ bidx,
                                              u64* __restrict__ keys) {
    int p = blockIdx.x * 256 + threadIdx.x;
    size_t idx = (size_t)(unsigned)bidx[p];
    float s = yolo[idx * 5 + 4];
    keys[p] = ((u64)__float_as_uint(s) << 32)
            | (u64)(0xFFFFFFFFu - (unsigned)p);
}

// Kernel 2: rank-sort. Keys are unique, so rank[p] = #{q : key[q] > key[p]}
// is the exact stable descending permutation. One wave per p; lanes scan 64
// keys per step via ballot+popc (keys are L2/L1-resident, 32 KB).
// Lane 0 then gathers the box and writes sorted arrays at position rank.
__global__ __launch_bounds__(256) void k_rank(const u64* __restrict__ keys,
                                              const float* __restrict__ yolo,
                                              const int* __restrict__ bidx,
                                              float4* __restrict__ sb,
                                              float* __restrict__ area,
                                              float* __restrict__ ss,
                                              int* __restrict__ sord) {
    #pragma clang fp contract(off)
    int gid = blockIdx.x * 256 + threadIdx.x;
    int p = gid >> 6;          // wave-uniform
    int lane = gid & 63;

    u64 kp = keys[p];
    int cnt = 0;
    for (int k = 0; k < 64; ++k) {
        u64 kq = keys[k * 64 + lane];            // coalesced
        cnt += __popcll(__ballot(kq > kp));      // wave-uniform increment
    }

    if (lane == 0) {
        int r = cnt;                              // rank = sorted position
        size_t idx = (size_t)(unsigned)bidx[p];
        float x1 = yolo[idx * 5 + 0];
        float y1 = yolo[idx * 5 + 1];
        float x2 = yolo[idx * 5 + 2];
        float y2 = yolo[idx * 5 + 3];
        float s  = __uint_as_float((unsigned)(kp >> 32));
        sb[r] = make_float4(x1, y1, x2, y2);
        area[r] = (x2 - x1 + 1.0f) * (y2 - y1 + 1.0f);   // same op order as reference
        ss[r] = s;
        sord[r] = p;
    }
}

// Kernel 3: one wave per row i. Step k: lanes compute IoU(i, k*64+lane);
// __ballot gives mask word k of row i. Lane k keeps word k, coalesced store.
__global__ __launch_bounds__(256) void k_mask(const float4* __restrict__ sb,
                                              const float* __restrict__ area,
                                              u64* __restrict__ mask) {
    #pragma clang fp contract(off)
    int gid = blockIdx.x * 256 + threadIdx.x;
    int i = gid >> 6;          // wave-uniform
    int lane = gid & 63;

    float4 bi = sb[i];
    float ai = area[i];
    u64 myword = 0ull;

    for (int k = 0; k < 64; ++k) {
        int j = k * 64 + lane;
        float4 bj = sb[j];
        float xx1 = fmaxf(bi.x, bj.x);
        float yy1 = fmaxf(bi.y, bj.y);
        float xx2 = fminf(bi.z, bj.z);
        float yy2 = fminf(bi.w, bj.w);
        float w = fmaxf(0.0f, xx2 - xx1 + 1.0f);
        float h = fmaxf(0.0f, yy2 - yy1 + 1.0f);
        float inter = w * h;
        float uni = (ai + area[j]) - inter;   // areas_i + areas_j - inter
        float iou = inter / uni;
        bool pred = (iou >= NMS_THRESH) && (j > i);
        u64 bal = __ballot(pred);
        if (k == lane) myword = bal;
    }
    mask[(size_t)i * 64 + lane] = myword;
}

// Kernel 4 (fused reduce + output), one block of 256 threads (4 waves).
// Staging is ASYNC DMA: waves 1..3 issue global_load_lds (1 KB/instr,
// ~11 instrs each) for chunk c+1 and immediately hit the barrier; the
// compiler-emitted vmcnt(0)-before-s_barrier drains them AFTER wave 0 has
// finished computing chunk c -- i.e. the loads get the whole compute phase
// (~2k cyc) to cover their ~900 cyc HBM/L3 latency. This replaces the
// previous dependent load->LDS-store round-trip pairs (~4.3 x ~900 cyc per
// helper thread per chunk) that kept the kernel at 210 us.
// Wave 0 per chunk:
//   Phase A (serial, register-only): greedy chain on diagonal words via
//     __shfl broadcasts; ~4 dependent VALU ops per step.
//   Phase B (parallel): branchless masked OR of kept rows' words -- 64
//     independent LDS loads (2-way bank alias = free on gfx950).
__global__ __launch_bounds__(256) void k_reduce_out(const u64* __restrict__ mask,
                                                    const float4* __restrict__ sb,
                                                    const float* __restrict__ ss,
                                                    const int* __restrict__ sord,
                                                    float* __restrict__ out) {
    __shared__ u64 stage[2][64 * 64];   // 2 x 32 KB
    __shared__ u64 keep_lds[64];
    const int tid = threadIdx.x;
    const int wid = tid >> 6;           // 0..3, wave-uniform
    const int lane = tid & 63;

    // preload chunk 0: 32 x 1KB DMA blocks over all 4 waves
    {
        const char* src = (const char*)mask;
        char* dst = (char*)stage[0];
        for (int b = wid; b < 32; b += 4)
            gload_lds16(src + b * 1024 + lane * 16, dst + b * 1024);
    }
    __syncthreads();

    u64 remv = 0ull;

    for (int c = 0; c < 64; ++c) {
        if (wid != 0) {
            if (c + 1 < 64) {   // waves 1..3: async-prefetch chunk c+1
                const char* src = (const char*)(mask + (size_t)(c + 1) * 4096);
                char* dst = (char*)stage[(c + 1) & 1];
                for (int b = wid - 1; b < 32; b += 3)
                    gload_lds16(src + b * 1024 + lane * 16, dst + b * 1024);
            }
        } else {
            const u64* buf = stage[c & 1];

            // ---- Phase A: serial chain on diagonal words (registers only)
            u64 bcu = buf[(lane << 6) + c];     // row `lane`'s word c
            u64 sup = __shfl(remv, c);          // remv word c (uniform)
            u64 kept = 0ull;
            #pragma unroll
            for (int u = 0; u < 64; ++u) {
                u64 bc_u = __shfl(bcu, u);                  // row u's word c (off-chain)
                u64 sbit = (sup >> u) & 1ull;               // 1 if row u suppressed
                kept |= (sbit ^ 1ull) << u;                 // side-chain
                sup  |= sbit ? 0ull : bc_u;                 // cndmask + or (critical)
            }

            // ---- Phase B: parallel masked OR of kept rows' mask words
            u64 acc = 0ull;
            #pragma unroll
            for (int u = 0; u < 64; ++u) {
                u64 m = buf[(u << 6) | lane];               // independent loads
                acc |= m & (0ull - ((kept >> u) & 1ull));
            }
            remv |= acc;
        }
        __syncthreads();   // drains helper waves' DMA (vmcnt(0) pre-barrier)
    }

    if (tid < 64) {
        u64 kw = ~remv;
        keep_lds[tid] = kw;
        int cnt = __popcll(kw);
        for (int off = 32; off > 0; off >>= 1) cnt += __shfl_down(cnt, off);
        if (tid == 0) out[(size_t)KBOX * 6] = (float)cnt;   // bbox_num
    }
    __syncthreads();

    // output fan-out: bbox_pred rows + nms_keep_idx (all elements every call)
    for (int p = tid; p < KBOX; p += 256) {
        bool keep = (keep_lds[p >> 6] >> (p & 63)) & 1ull;
        float4 b = sb[p];
        float s = ss[p];
        int o = sord[p];

        float* row = out + (size_t)p * 6;
        row[0] = 0.0f;
        row[1] = keep ? s   : 0.0f;
        row[2] = keep ? b.x : 0.0f;
        row[3] = keep ? b.y : 0.0f;
        row[4] = keep ? b.z : 0.0f;
        row[5] = keep ? b.w : 0.0f;

        out[(size_t)KBOX * 6 + 1 + p] = keep ? (float)o : -1.0f;
    }
}

extern "C" void kernel_launch(void* const* d_in, const int* in_sizes, int n_in,
                              void* d_out, int out_size, void* d_ws, size_t ws_size,
                              hipStream_t stream) {
    const float* yolo = (const float*)d_in[0];   // [4e6, 5] f32
    const int* bidx   = (const int*)d_in[1];     // [4096] i32
    float* out = (float*)d_out;                  // 4096*6 + 1 + 4096 floats

    char* ws = (char*)d_ws;                      // ~2.15 MB used
    float4* sb  = (float4*)(ws + WS_SB);
    float* area = (float*)(ws + WS_AREA);
    float* ss   = (float*)(ws + WS_SS);
    int* sord   = (int*)(ws + WS_ORD);
    u64* keys   = (u64*)(ws + WS_KEYS);
    u64* mask   = (u64*)(ws + WS_MASK);

    k_keys<<<KBOX / 256, 256, 0, stream>>>(yolo, bidx, keys);
    k_rank<<<(KBOX * 64) / 256, 256, 0, stream>>>(keys, yolo, bidx, sb, area, ss, sord);
    k_mask<<<(KBOX * 64) / 256, 256, 0, stream>>>(sb, area, mask);
    k_reduce_out<<<1, 256, 0, stream>>>(mask, sb, ss, sord, out);
}